// Round 11
// baseline (1900.340 us; speedup 1.0000x reference)
//
#include <hip/hip_runtime.h>

typedef _Float16 half_t;
typedef unsigned short u16;
typedef half_t half8 __attribute__((ext_vector_type(8)));
typedef float f32x4 __attribute__((ext_vector_type(4)));
typedef u16 u16x8 __attribute__((ext_vector_type(8)));
typedef u16 u16x4 __attribute__((ext_vector_type(4)));

// ---------- helpers ----------
static __device__ __forceinline__ float rcp_f(float x) { return __builtin_amdgcn_rcpf(x); }
static __device__ __forceinline__ float sigm_f(float x) { return rcp_f(1.0f + __expf(-x)); }
static __device__ __forceinline__ float tanh_f(float x) {
  float e = __expf(2.0f * x);  // inf-safe: rcp(inf)=0 -> 1 ; e=0 -> -1
  return 1.0f - 2.0f * rcp_f(e + 1.0f);
}
static __device__ __forceinline__ float h2f(u16 u) { union { u16 u; half_t h; } c; c.u = u; return (float)c.h; }
static __device__ __forceinline__ u16 f2h(float f) { union { u16 u; half_t h; } c; c.h = (half_t)f; return c.u; }

// swizzled offset (u16 units) into a [16][256] f16 LDS tile
static __device__ __forceinline__ int hoff2(int bb, int j) {
  int slot = j >> 3;
  int sw = (slot & ~7) | ((slot ^ bb) & 7);
  return bb * 256 + (sw << 3) + (j & 7);
}

// raw barrier: drain LDS only, leave VMEM in flight across the step boundary
#define STEP_BARRIER()                                         \
  do {                                                         \
    asm volatile("s_waitcnt lgkmcnt(0)" ::: "memory");         \
    __builtin_amdgcn_s_barrier();                              \
    asm volatile("" ::: "memory");                             \
  } while (0)

// ---------- per-layer launch tables (by-value kernel args) ----------
struct SP {
  const u16* Whh; const float* bhh; const u16* gi;
  const float* hin; float* hout; u16* outb; float* dfin;
};
struct STab { SP e[6]; };
struct GP { const u16* A; const u16* W; const float* bias; u16* gi; int K; };
struct GTab { GP e[6]; };

// ---------- fp32 -> fp16 convert ----------
__global__ void k_cvt(const float* __restrict__ src, u16* __restrict__ dst, int n) {
  int i = (blockIdx.x * blockDim.x + threadIdx.x) * 4;
  if (i >= n) return;
  float4 v = *(const float4*)(src + i);
  u16x4 o;
  o[0] = f2h(v.x); o[1] = f2h(v.y); o[2] = f2h(v.z); o[3] = f2h(v.w);
  *(u16x4*)(dst + i) = o;
}

// ---------- combined bias: comb = bih + (row<512 ? bhh : 0) ----------
__global__ void k_bias(const float* __restrict__ bih, const float* __restrict__ bhh,
                       float* __restrict__ comb) {
  int i = blockIdx.x * 256 + threadIdx.x;
  if (i >= 6 * 768) return;
  int r = i % 768;
  comb[i] = bih[i] + (r < 512 ? bhh[i] : 0.0f);
}

// ---------- gi GEMM (multi-layer): C[m][n] = A[m][k]*W[n][k] + bias[n] ----------
__global__ __launch_bounds__(256) void k_gemm(GTab tab) {
  const GP gp = tab.e[blockIdx.z];
  const u16* __restrict__ A = gp.A;
  const u16* __restrict__ W = gp.W;
  const float* __restrict__ bias = gp.bias;
  u16* __restrict__ gi = gp.gi;
  const int K = gp.K;

  __shared__ u16 Ab[2][128 * 32];
  __shared__ u16 Bb[2][128 * 32];
  const int tid = threadIdx.x;
  const int l = tid & 63, w = tid >> 6;
  const int wm = w & 1, wn = w >> 1;
  const int ln = l & 15, q = l >> 4;
  const int m0 = blockIdx.x * 128;
  const int n0 = blockIdx.y * 128;
  const int NT = K >> 5;

  float bz[4];
#pragma unroll
  for (int nt = 0; nt < 4; ++nt) bz[nt] = bias[n0 + wn * 64 + nt * 16 + ln];

  f32x4 acc[4][4];
#pragma unroll
  for (int mt = 0; mt < 4; ++mt)
#pragma unroll
    for (int nt = 0; nt < 4; ++nt) acc[mt][nt] = (f32x4){bz[nt], bz[nt], bz[nt], bz[nt]};

  auto stage = [&](int buf, int kt) {
    const int k0 = kt * 32;
#pragma unroll
    for (int qq = 0; qq < 2; ++qq) {
      int e = qq * 1024 + l * 16;
      int row = w * 32 + (e >> 6);
      int kk = (e & 63) >> 1;
      const u16* ga = A + (size_t)(m0 + row) * K + k0 + kk;
      const u16* gb = W + (size_t)(n0 + row) * K + k0 + kk;
      __builtin_amdgcn_global_load_lds((const __attribute__((address_space(1))) void*)ga,
                                       (__attribute__((address_space(3))) void*)&Ab[buf][row * 32 + kk],
                                       16, 0, 0);
      __builtin_amdgcn_global_load_lds((const __attribute__((address_space(1))) void*)gb,
                                       (__attribute__((address_space(3))) void*)&Bb[buf][row * 32 + kk],
                                       16, 0, 0);
    }
  };

  stage(0, 0);
  int cur = 0;
  for (int kt = 0; kt < NT; ++kt) {
    __syncthreads();  // staged tile must be complete
    if (kt + 1 < NT) stage(cur ^ 1, kt + 1);
    union { u16x8 u; half8 h; } af[4], bf[4];
#pragma unroll
    for (int mt = 0; mt < 4; ++mt)
      af[mt].u = *(const u16x8*)&Ab[cur][(wm * 64 + mt * 16 + ln) * 32 + q * 8];
#pragma unroll
    for (int nt = 0; nt < 4; ++nt)
      bf[nt].u = *(const u16x8*)&Bb[cur][(wn * 64 + nt * 16 + ln) * 32 + q * 8];
#pragma unroll
    for (int mt = 0; mt < 4; ++mt)
#pragma unroll
      for (int nt = 0; nt < 4; ++nt)
        acc[mt][nt] = __builtin_amdgcn_mfma_f32_16x16x32_f16(af[mt].h, bf[nt].h, acc[mt][nt], 0, 0, 0);
    cur ^= 1;
  }

#pragma unroll
  for (int mt = 0; mt < 4; ++mt) {
    int m = m0 + wm * 64 + mt * 16 + q * 4;
    int tloc = m >> 8, blk = (m >> 4) & 15, bb0 = m & 15;
#pragma unroll
    for (int nt = 0; nt < 4; ++nt) {
      int n = n0 + wn * 64 + nt * 16 + ln;
      u16x4 o;
#pragma unroll
      for (int i = 0; i < 4; ++i) o[i] = f2h(acc[mt][nt][i]);
      *(u16x4*)&gi[(((size_t)tloc * 16 + blk) * 768 + n) * 16 + bb0] = o;
    }
  }
}

// ---------- persistent-weight GRU scan (multi-layer wavefront) ----------
// grid (16, nact): blockIdx.x = batch slice, blockIdx.y -> layer via table.
__global__ __launch_bounds__(512, 2) void k_scan(STab tab, int tcount) {
  const SP p = tab.e[blockIdx.y];
  const u16* __restrict__ Whh = p.Whh;
  const float* __restrict__ bhh = p.bhh;
  const u16* __restrict__ gi = p.gi;
  const float* hin = p.hin;
  float* hout = p.hout;
  u16* __restrict__ outb = p.outb;
  float* __restrict__ dfin = p.dfin;

  __shared__ u16 hl[2][16 * 256];        // 16 KB
  __shared__ u16 wn[8][2][8][512];       // 128 KB: n-gate weights, per-wave slices
  const int tid = threadIdx.x;
  const int l = tid & 63, w = tid >> 6;
  const int ln = l & 15, q = l >> 4;
  const int j0 = w * 32;
  const int bx = blockIdx.x;
  const int bb0g = bx * 16;

  union u128 { u16x8 u; half8 h; };

  // resident weight fragments, gates r,z: 128 VGPRs (AGPR-parked overflow is
  // cheap reg-reg, NOT memory)
  u128 Bw[2][2][8];
#pragma unroll
  for (int g = 0; g < 2; ++g)
#pragma unroll
    for (int jt = 0; jt < 2; ++jt) {
      int row = g * 256 + j0 + jt * 16 + ln;
#pragma unroll
      for (int kf = 0; kf < 8; ++kf)
        Bw[g][jt][kf].u = *(const u16x8*)&Whh[row * 256 + kf * 32 + q * 8];
    }
#pragma unroll
  for (int g = 0; g < 2; ++g)
#pragma unroll
    for (int jt = 0; jt < 2; ++jt)
#pragma unroll
      for (int kf = 0; kf < 8; ++kf)
        asm volatile("" : "+v"(Bw[g][jt][kf].u));

  // n-gate weights -> LDS (per-wave slice, B-frag lane order)
#pragma unroll
  for (int jt = 0; jt < 2; ++jt)
#pragma unroll
    for (int kf = 0; kf < 8; ++kf) {
      int row = 512 + j0 + jt * 16 + ln;
      *(u16x8*)&wn[w][jt][kf][l * 8] = *(const u16x8*)&Whh[row * 256 + kf * 32 + q * 8];
    }

  // n-gate recurrent bias
  float bn[2];
  bn[0] = bhh[512 + j0 + ln];
  bn[1] = bhh[512 + j0 + 16 + ln];

  // fp32 recurrent state
  float hst[2][4];
#pragma unroll
  for (int jt = 0; jt < 2; ++jt)
#pragma unroll
    for (int i = 0; i < 4; ++i)
      hst[jt][i] = hin[(bb0g + q * 4 + i) * 256 + j0 + jt * 16 + ln];

  // seed h LDS (buffer 0)
#pragma unroll
  for (int jt = 0; jt < 2; ++jt)
#pragma unroll
    for (int i = 0; i < 4; ++i)
      hl[0][hoff2(q * 4 + i, j0 + jt * 16 + ln)] = f2h(hst[jt][i]);

  // gv for t=0
  u16x4 gv[3][2];
  {
    const u16* p2 = gi + ((size_t)bx * 768 + j0 + ln) * 16 + q * 4;
#pragma unroll
    for (int g = 0; g < 3; ++g)
#pragma unroll
      for (int jt = 0; jt < 2; ++jt)
        gv[g][jt] = *(const u16x4*)(p2 + (g * 256 + jt * 16) * 16);
  }

  int cur = 0;
  for (int t = 0; t < tcount; ++t) {
    STEP_BARRIER();  // hl[cur] complete; VMEM stays in flight
    u16* hlc = &hl[cur][0];
    u16* hln = &hl[cur ^ 1][0];

    // write h entering this step (local output index t-1; dup at t==0 is
    // overwritten by the next step's write)
    {
      int ot = t - 1; if (ot < 0) ot = 0;
      int obb = tid >> 5, oj = (tid & 31) << 3;
      u16x8 v = *(const u16x8*)&hlc[hoff2(obb, oj)];
      *(u16x8*)&outb[((size_t)ot * 256 + bb0g + obb) * 256 + oj] = v;
    }

    f32x4 ar[2], az[2], an[2];
#pragma unroll
    for (int jt = 0; jt < 2; ++jt) {
      ar[jt] = (f32x4){0.f, 0.f, 0.f, 0.f};
      az[jt] = (f32x4){0.f, 0.f, 0.f, 0.f};
      an[jt] = (f32x4){bn[jt], bn[jt], bn[jt], bn[jt]};
    }

#pragma unroll
    for (int kf = 0; kf < 8; ++kf) {
      u128 av, w0, w1;
      av.u = *(const u16x8*)&hlc[hoff2(ln, kf * 32 + q * 8)];
      w0.u = *(const u16x8*)&wn[w][0][kf][l * 8];
      w1.u = *(const u16x8*)&wn[w][1][kf][l * 8];
#pragma unroll
      for (int jt = 0; jt < 2; ++jt) {
        ar[jt] = __builtin_amdgcn_mfma_f32_16x16x32_f16(av.h, Bw[0][jt][kf].h, ar[jt], 0, 0, 0);
        az[jt] = __builtin_amdgcn_mfma_f32_16x16x32_f16(av.h, Bw[1][jt][kf].h, az[jt], 0, 0, 0);
      }
      an[0] = __builtin_amdgcn_mfma_f32_16x16x32_f16(av.h, w0.h, an[0], 0, 0, 0);
      an[1] = __builtin_amdgcn_mfma_f32_16x16x32_f16(av.h, w1.h, an[1], 0, 0, 0);
    }

    // elementwise + state update + LDS write for next step
#pragma unroll
    for (int jt = 0; jt < 2; ++jt)
#pragma unroll
      for (int i = 0; i < 4; ++i) {
        float r = sigm_f(h2f(gv[0][jt][i]) + ar[jt][i]);
        float z = sigm_f(h2f(gv[1][jt][i]) + az[jt][i]);
        float n = tanh_f(h2f(gv[2][jt][i]) + r * an[jt][i]);
        float hv = n + z * (hst[jt][i] - n);
        hst[jt][i] = hv;
        hln[hoff2(q * 4 + i, j0 + jt * 16 + ln)] = f2h(hv);
      }

    // prefetch gv for t+1
    {
      int tn = t + 1 < tcount ? t + 1 : tcount - 1;
      const u16* p2 = gi + (((size_t)tn * 16 + bx) * 768 + j0 + ln) * 16 + q * 4;
#pragma unroll
      for (int g = 0; g < 3; ++g)
#pragma unroll
        for (int jt = 0; jt < 2; ++jt)
          gv[g][jt] = *(const u16x4*)(p2 + (g * 256 + jt * 16) * 16);
    }
    cur ^= 1;
  }

  STEP_BARRIER();
  {  // final output row of this chunk
    int obb = tid >> 5, oj = (tid & 31) << 3;
    u16x8 v = *(const u16x8*)&hl[cur][hoff2(obb, oj)];
    *(u16x8*)&outb[((size_t)(tcount - 1) * 256 + bb0g + obb) * 256 + oj] = v;
  }
  // persist fp32 state + h_n slice (ascending chunk order => last chunk wins)
#pragma unroll
  for (int jt = 0; jt < 2; ++jt)
#pragma unroll
    for (int i = 0; i < 4; ++i) {
      int idx = (bb0g + q * 4 + i) * 256 + j0 + jt * 16 + ln;
      hout[idx] = hst[jt][i];
      dfin[idx] = hst[jt][i];
    }
}

// ---------- host: launch-wavefront layer pipeline ----------
extern "C" void kernel_launch(void* const* d_in, const int* in_sizes, int n_in,
                              void* d_out, int out_size, void* d_ws, size_t ws_size,
                              hipStream_t stream) {
  const float* x    = (const float*)d_in[0];
  const float* h0   = (const float*)d_in[1];
  const float* wih0 = (const float*)d_in[2];
  const float* wih  = (const float*)d_in[3];
  const float* whh  = (const float*)d_in[4];
  const float* bih  = (const float*)d_in[5];
  const float* bhh  = (const float*)d_in[6];
  float* out = (float*)d_out;
  char* ws = (char*)d_ws;

  const int NL = 6, T = 512;
  const size_t sz_x = (size_t)T * 256 * 128 * 2;     // 33.55 MB
  const size_t sz_w = (size_t)NL * 768 * 256 * 2;    // 2.36 MB

  // fixed region
  size_t o_x = 0;
  size_t o_wih = o_x + sz_x;
  size_t o_whh = o_wih + sz_w;
  size_t o_comb = o_whh + sz_w;
  size_t o_h = o_comb + (size_t)NL * 768 * 4;
  size_t o_dyn = o_h + (size_t)NL * 65536 * 4;

  // C=32 minimizes (512/C+5)*(2.03*C + P) given measured s,g,P (R10 model);
  // shrink further only if workspace-constrained.
  int C = 32;
  while (C > 8 && o_dyn + (size_t)C * (NL * 2 * 131072 + NL * 393216) > ws_size) C >>= 1;
  const int NC = T / C;

  size_t o_ring = o_dyn;
  size_t o_gi = o_ring + (size_t)NL * 2 * C * 131072;

  u16* xf    = (u16*)(ws + o_x);
  u16* wihf  = (u16*)(ws + o_wih);
  u16* whhf  = (u16*)(ws + o_whh);
  float* comb = (float*)(ws + o_comb);
  float* hstate = (float*)(ws + o_h);
  u16* ringf = (u16*)(ws + o_ring);
  u16* gif   = (u16*)(ws + o_gi);

  auto ringptr = [&](int l, int c) -> u16* {
    return ringf + ((size_t)l * 2 + (c & 1)) * ((size_t)C * 65536);
  };

  auto cvt = [&](const float* s, u16* d, int n) {
    k_cvt<<<dim3((n / 4 + 255) / 256), dim3(256), 0, stream>>>(s, d, n);
  };
  cvt(x, xf, T * 256 * 128);
  cvt(wih0, wihf, 768 * 128);
  cvt(wih, wihf + 196608, 5 * 768 * 256);
  cvt(whh, whhf, 6 * 768 * 256);
  k_bias<<<dim3(18), dim3(256), 0, stream>>>(bih, bhh, comb);

  for (int wv = 0; wv < NL + NC - 1; ++wv) {
    int lmin = wv - (NC - 1); if (lmin < 0) lmin = 0;
    int lmax = wv < NL - 1 ? wv : NL - 1;
    int nact = lmax - lmin + 1;

    GTab gt; STab st;
    for (int zi = 0; zi < nact; ++zi) {
      int lyr = lmin + zi, c = wv - lyr;
      u16* gi_l = gif + (size_t)lyr * C * 196608;
      // GEMM params
      gt.e[zi].A = (lyr == 0) ? (xf + (size_t)c * C * 32768) : ringptr(lyr - 1, c);
      gt.e[zi].W = wihf + (size_t)lyr * 196608;
      gt.e[zi].bias = comb + lyr * 768;
      gt.e[zi].gi = gi_l;
      gt.e[zi].K = lyr ? 256 : 128;
      // scan params
      st.e[zi].Whh = whhf + (size_t)lyr * 196608;
      st.e[zi].bhh = bhh + lyr * 768;
      st.e[zi].gi = gi_l;
      st.e[zi].hin = (c == 0) ? (h0 + lyr * 65536) : (hstate + lyr * 65536);
      st.e[zi].hout = hstate + lyr * 65536;
      st.e[zi].outb = ringptr(lyr, c);
      st.e[zi].dfin = out + lyr * 65536;
    }
    k_gemm<<<dim3(2 * C, 6, nact), dim3(256), 0, stream>>>(gt);
    k_scan<<<dim3(16, nact), dim3(512), 0, stream>>>(st, C);
  }
}

// Round 14
// 1773.057 us; speedup vs baseline: 1.0718x; 1.0718x over previous
//
#include <hip/hip_runtime.h>

typedef _Float16 half_t;
typedef unsigned short u16;
typedef half_t half8 __attribute__((ext_vector_type(8)));
typedef float f32x4 __attribute__((ext_vector_type(4)));
typedef u16 u16x8 __attribute__((ext_vector_type(8)));
typedef u16 u16x4 __attribute__((ext_vector_type(4)));

// ---------- helpers ----------
static __device__ __forceinline__ float rcp_f(float x) { return __builtin_amdgcn_rcpf(x); }
static __device__ __forceinline__ float sigm_f(float x) { return rcp_f(1.0f + __expf(-x)); }
static __device__ __forceinline__ float tanh_f(float x) {
  float e = __expf(2.0f * x);  // inf-safe: rcp(inf)=0 -> 1 ; e=0 -> -1
  return 1.0f - 2.0f * rcp_f(e + 1.0f);
}
static __device__ __forceinline__ float h2f(u16 u) { union { u16 u; half_t h; } c; c.u = u; return (float)c.h; }
static __device__ __forceinline__ u16 f2h(float f) { union { u16 u; half_t h; } c; c.h = (half_t)f; return c.u; }

// swizzled offset (u16 units) into a [16][256] f16 LDS tile
static __device__ __forceinline__ int hoff2(int bb, int j) {
  int slot = j >> 3;
  int sw = (slot & ~7) | ((slot ^ bb) & 7);
  return bb * 256 + (sw << 3) + (j & 7);
}

// raw barrier: drain LDS only, leave VMEM in flight across the step boundary
#define STEP_BARRIER()                                         \
  do {                                                         \
    asm volatile("s_waitcnt lgkmcnt(0)" ::: "memory");         \
    __builtin_amdgcn_s_barrier();                              \
    asm volatile("" ::: "memory");                             \
  } while (0)

// ---------- per-layer launch tables (by-value kernel args) ----------
struct SP {
  const u16* Wf;  const float* bhh; const u16* gi;
  const float* hin; float* hout; u16* outb; float* dfin;
};
struct STab { SP e[6]; };
struct GP { const u16* A; const u16* W; const float* bias; u16* gi; int K; };
struct GTab { GP e[6]; };

// ---------- fp32 -> fp16 convert ----------
__global__ void k_cvt(const float* __restrict__ src, u16* __restrict__ dst, int n) {
  int i = (blockIdx.x * blockDim.x + threadIdx.x) * 4;
  if (i >= n) return;
  float4 v = *(const float4*)(src + i);
  u16x4 o;
  o[0] = f2h(v.x); o[1] = f2h(v.y); o[2] = f2h(v.z); o[3] = f2h(v.w);
  *(u16x4*)(dst + i) = o;
}

// ---------- combined bias: comb = bih + (row<512 ? bhh : 0) ----------
__global__ void k_bias(const float* __restrict__ bih, const float* __restrict__ bhh,
                       float* __restrict__ comb) {
  int i = blockIdx.x * 256 + threadIdx.x;
  if (i >= 6 * 768) return;
  int r = i % 768;
  comb[i] = bih[i] + (r < 512 ? bhh[i] : 0.0f);
}

// ---------- weight prep: repack Whh f16 into fragment-ordered blocks ----------
// Per (layer l, wave w): contiguous 24576 u16 = 48 KB:
//   rz : off = ((g*2+jt)*8+kf)*512 + lane*8 + e
//        = Whh_l[(g*256 + w*32 + jt*16 + (lane&15))*256 + kf*32 + (lane>>4)*8 + e]
//   n  : off = 16384 + (jt*8+kf)*512 + lane*8 + e
//        = Whh_l[(512  + w*32 + jt*16 + (lane&15))*256 + kf*32 + (lane>>4)*8 + e]
__global__ void k_wprep(const u16* __restrict__ whhf, u16* __restrict__ wfrag) {
  int gid = blockIdx.x * 256 + threadIdx.x;     // one 16B group per thread
  if (gid >= 147456) return;                    // 6*8*3072
  int lw = gid / 3072, grp = gid % 3072;
  int l = lw >> 3, w = lw & 7;
  const u16* wl = whhf + (size_t)l * 196608;
  int row, col, off;
  if (grp < 2048) {  // rz
    int sec = grp >> 6, lane = grp & 63;        // sec 0..31
    int g = sec >> 4, jt = (sec >> 3) & 1, kf = sec & 7;
    row = g * 256 + w * 32 + jt * 16 + (lane & 15);
    col = kf * 32 + (lane >> 4) * 8;
    off = sec * 512 + lane * 8;
  } else {           // n
    int grp2 = grp - 2048;
    int sec = grp2 >> 6, lane = grp2 & 63;      // sec 0..15
    int jt = sec >> 3, kf = sec & 7;
    row = 512 + w * 32 + jt * 16 + (lane & 15);
    col = kf * 32 + (lane >> 4) * 8;
    off = 16384 + sec * 512 + lane * 8;
  }
  *(u16x8*)&wfrag[((size_t)lw) * 24576 + off] = *(const u16x8*)&wl[row * 256 + col];
}

// ---------- gi GEMM (multi-layer): C[m][n] = A[m][k]*W[n][k] + bias[n] ----------
__global__ __launch_bounds__(256) void k_gemm(GTab tab) {
  const GP gp = tab.e[blockIdx.z];
  const u16* __restrict__ A = gp.A;
  const u16* __restrict__ W = gp.W;
  const float* __restrict__ bias = gp.bias;
  u16* __restrict__ gi = gp.gi;
  const int K = gp.K;

  __shared__ u16 Ab[2][128 * 32];
  __shared__ u16 Bb[2][128 * 32];
  const int tid = threadIdx.x;
  const int l = tid & 63, w = tid >> 6;
  const int wm = w & 1, wn = w >> 1;
  const int ln = l & 15, q = l >> 4;
  const int m0 = blockIdx.x * 128;
  const int n0 = blockIdx.y * 128;
  const int NT = K >> 5;

  float bz[4];
#pragma unroll
  for (int nt = 0; nt < 4; ++nt) bz[nt] = bias[n0 + wn * 64 + nt * 16 + ln];

  f32x4 acc[4][4];
#pragma unroll
  for (int mt = 0; mt < 4; ++mt)
#pragma unroll
    for (int nt = 0; nt < 4; ++nt) acc[mt][nt] = (f32x4){bz[nt], bz[nt], bz[nt], bz[nt]};

  auto stage = [&](int buf, int kt) {
    const int k0 = kt * 32;
#pragma unroll
    for (int qq = 0; qq < 2; ++qq) {
      int e = qq * 1024 + l * 16;
      int row = w * 32 + (e >> 6);
      int kk = (e & 63) >> 1;
      const u16* ga = A + (size_t)(m0 + row) * K + k0 + kk;
      const u16* gb = W + (size_t)(n0 + row) * K + k0 + kk;
      __builtin_amdgcn_global_load_lds((const __attribute__((address_space(1))) void*)ga,
                                       (__attribute__((address_space(3))) void*)&Ab[buf][row * 32 + kk],
                                       16, 0, 0);
      __builtin_amdgcn_global_load_lds((const __attribute__((address_space(1))) void*)gb,
                                       (__attribute__((address_space(3))) void*)&Bb[buf][row * 32 + kk],
                                       16, 0, 0);
    }
  };

  stage(0, 0);
  int cur = 0;
  for (int kt = 0; kt < NT; ++kt) {
    __syncthreads();  // staged tile must be complete
    if (kt + 1 < NT) stage(cur ^ 1, kt + 1);
    union { u16x8 u; half8 h; } af[4], bf[4];
#pragma unroll
    for (int mt = 0; mt < 4; ++mt)
      af[mt].u = *(const u16x8*)&Ab[cur][(wm * 64 + mt * 16 + ln) * 32 + q * 8];
#pragma unroll
    for (int nt = 0; nt < 4; ++nt)
      bf[nt].u = *(const u16x8*)&Bb[cur][(wn * 64 + nt * 16 + ln) * 32 + q * 8];
#pragma unroll
    for (int mt = 0; mt < 4; ++mt)
#pragma unroll
      for (int nt = 0; nt < 4; ++nt)
        acc[mt][nt] = __builtin_amdgcn_mfma_f32_16x16x32_f16(af[mt].h, bf[nt].h, acc[mt][nt], 0, 0, 0);
    cur ^= 1;
  }

#pragma unroll
  for (int mt = 0; mt < 4; ++mt) {
    int m = m0 + wm * 64 + mt * 16 + q * 4;
    int tloc = m >> 8, blk = (m >> 4) & 15, bb0 = m & 15;
#pragma unroll
    for (int nt = 0; nt < 4; ++nt) {
      int n = n0 + wn * 64 + nt * 16 + ln;
      u16x4 o;
#pragma unroll
      for (int i = 0; i < 4; ++i) o[i] = f2h(acc[mt][nt][i]);
      *(u16x4*)&gi[(((size_t)tloc * 16 + blk) * 768 + n) * 16 + bb0] = o;
    }
  }
}

// ---------- persistent-weight GRU scan (multi-layer wavefront) ----------
// grid (16, nact). Weights read from the fragment-ordered wfrag buffer:
// fully coalesced register loads (r,z) + global_load_lds staging (n-gate).
__global__ __launch_bounds__(512, 2) void k_scan(STab tab, int tcount) {
  const SP p = tab.e[blockIdx.y];
  const u16* __restrict__ Wf = p.Wf;     // layer base in wfrag
  const float* __restrict__ bhh = p.bhh;
  const u16* __restrict__ gi = p.gi;
  const float* hin = p.hin;
  float* hout = p.hout;
  u16* __restrict__ outb = p.outb;
  float* __restrict__ dfin = p.dfin;

  __shared__ u16 hl[2][16 * 256];        // 16 KB
  __shared__ u16 wn[8][2][8][512];       // 128 KB: n-gate weights, per-wave slices
  const int tid = threadIdx.x;
  const int l = tid & 63, w = tid >> 6;
  const int ln = l & 15, q = l >> 4;
  const int j0 = w * 32;
  const int bx = blockIdx.x;
  const int bb0g = bx * 16;

  union u128 { u16x8 u; half8 h; };

  const u16* wb = Wf + (size_t)w * 24576;  // this wave's 48 KB fragment block

  // r,z weight fragments: 32 coalesced b128 loads (512 B/lane contiguous)
  u128 Bw[2][2][8];
#pragma unroll
  for (int g = 0; g < 2; ++g)
#pragma unroll
    for (int jt = 0; jt < 2; ++jt)
#pragma unroll
      for (int kf = 0; kf < 8; ++kf)
        Bw[g][jt][kf].u = *(const u16x8*)&wb[(((g * 2 + jt) * 8) + kf) * 512 + l * 8];
#pragma unroll
  for (int g = 0; g < 2; ++g)
#pragma unroll
    for (int jt = 0; jt < 2; ++jt)
#pragma unroll
      for (int kf = 0; kf < 8; ++kf)
        asm volatile("" : "+v"(Bw[g][jt][kf].u));

  // n-gate weights -> LDS via async global->LDS (dest = uniform base + lane*16)
#pragma unroll
  for (int jt = 0; jt < 2; ++jt)
#pragma unroll
    for (int kf = 0; kf < 8; ++kf)
      __builtin_amdgcn_global_load_lds(
          (const __attribute__((address_space(1))) void*)&wb[16384 + (jt * 8 + kf) * 512 + l * 8],
          (__attribute__((address_space(3))) void*)&wn[w][jt][kf][l * 8], 16, 0, 0);

  // n-gate recurrent bias
  float bn[2];
  bn[0] = bhh[512 + j0 + ln];
  bn[1] = bhh[512 + j0 + 16 + ln];

  // fp32 recurrent state
  float hst[2][4];
#pragma unroll
  for (int jt = 0; jt < 2; ++jt)
#pragma unroll
    for (int i = 0; i < 4; ++i)
      hst[jt][i] = hin[(bb0g + q * 4 + i) * 256 + j0 + jt * 16 + ln];

  // seed h LDS (buffer 0)
#pragma unroll
  for (int jt = 0; jt < 2; ++jt)
#pragma unroll
    for (int i = 0; i < 4; ++i)
      hl[0][hoff2(q * 4 + i, j0 + jt * 16 + ln)] = f2h(hst[jt][i]);

  // gv for t=0
  u16x4 gv[3][2];
  {
    const u16* p2 = gi + ((size_t)bx * 768 + j0 + ln) * 16 + q * 4;
#pragma unroll
    for (int g = 0; g < 3; ++g)
#pragma unroll
      for (int jt = 0; jt < 2; ++jt)
        gv[g][jt] = *(const u16x4*)(p2 + (g * 256 + jt * 16) * 16);
  }

  // drain wn staging (global_load_lds completion is not register-tracked)
  asm volatile("s_waitcnt vmcnt(0)" ::: "memory");

  int cur = 0;
  for (int t = 0; t < tcount; ++t) {
    STEP_BARRIER();  // hl[cur] complete; VMEM stays in flight
    u16* hlc = &hl[cur][0];
    u16* hln = &hl[cur ^ 1][0];

    // write h entering this step (local output index t-1; dup at t==0 is
    // overwritten by the next step's write)
    {
      int ot = t - 1; if (ot < 0) ot = 0;
      int obb = tid >> 5, oj = (tid & 31) << 3;
      u16x8 v = *(const u16x8*)&hlc[hoff2(obb, oj)];
      *(u16x8*)&outb[((size_t)ot * 256 + bb0g + obb) * 256 + oj] = v;
    }

    f32x4 ar[2], az[2], an[2];
#pragma unroll
    for (int jt = 0; jt < 2; ++jt) {
      ar[jt] = (f32x4){0.f, 0.f, 0.f, 0.f};
      az[jt] = (f32x4){0.f, 0.f, 0.f, 0.f};
      an[jt] = (f32x4){bn[jt], bn[jt], bn[jt], bn[jt]};
    }

#pragma unroll
    for (int kf = 0; kf < 8; ++kf) {
      u128 av, w0, w1;
      av.u = *(const u16x8*)&hlc[hoff2(ln, kf * 32 + q * 8)];
      w0.u = *(const u16x8*)&wn[w][0][kf][l * 8];
      w1.u = *(const u16x8*)&wn[w][1][kf][l * 8];
#pragma unroll
      for (int jt = 0; jt < 2; ++jt) {
        ar[jt] = __builtin_amdgcn_mfma_f32_16x16x32_f16(av.h, Bw[0][jt][kf].h, ar[jt], 0, 0, 0);
        az[jt] = __builtin_amdgcn_mfma_f32_16x16x32_f16(av.h, Bw[1][jt][kf].h, az[jt], 0, 0, 0);
      }
      an[0] = __builtin_amdgcn_mfma_f32_16x16x32_f16(av.h, w0.h, an[0], 0, 0, 0);
      an[1] = __builtin_amdgcn_mfma_f32_16x16x32_f16(av.h, w1.h, an[1], 0, 0, 0);
    }

    // elementwise + state update + LDS write for next step
#pragma unroll
    for (int jt = 0; jt < 2; ++jt)
#pragma unroll
      for (int i = 0; i < 4; ++i) {
        float r = sigm_f(h2f(gv[0][jt][i]) + ar[jt][i]);
        float z = sigm_f(h2f(gv[1][jt][i]) + az[jt][i]);
        float n = tanh_f(h2f(gv[2][jt][i]) + r * an[jt][i]);
        float hv = n + z * (hst[jt][i] - n);
        hst[jt][i] = hv;
        hln[hoff2(q * 4 + i, j0 + jt * 16 + ln)] = f2h(hv);
      }

    // prefetch gv for t+1
    {
      int tn = t + 1 < tcount ? t + 1 : tcount - 1;
      const u16* p2 = gi + (((size_t)tn * 16 + bx) * 768 + j0 + ln) * 16 + q * 4;
#pragma unroll
      for (int g = 0; g < 3; ++g)
#pragma unroll
        for (int jt = 0; jt < 2; ++jt)
          gv[g][jt] = *(const u16x4*)(p2 + (g * 256 + jt * 16) * 16);
    }
    cur ^= 1;
  }

  STEP_BARRIER();
  {  // final output row of this chunk
    int obb = tid >> 5, oj = (tid & 31) << 3;
    u16x8 v = *(const u16x8*)&hl[cur][hoff2(obb, oj)];
    *(u16x8*)&outb[((size_t)(tcount - 1) * 256 + bb0g + obb) * 256 + oj] = v;
  }
  // persist fp32 state + h_n slice (ascending chunk order => last chunk wins)
#pragma unroll
  for (int jt = 0; jt < 2; ++jt)
#pragma unroll
    for (int i = 0; i < 4; ++i) {
      int idx = (bb0g + q * 4 + i) * 256 + j0 + jt * 16 + ln;
      hout[idx] = hst[jt][i];
      dfin[idx] = hst[jt][i];
    }
}

// ---------- host: launch-wavefront layer pipeline ----------
extern "C" void kernel_launch(void* const* d_in, const int* in_sizes, int n_in,
                              void* d_out, int out_size, void* d_ws, size_t ws_size,
                              hipStream_t stream) {
  const float* x    = (const float*)d_in[0];
  const float* h0   = (const float*)d_in[1];
  const float* wih0 = (const float*)d_in[2];
  const float* wih  = (const float*)d_in[3];
  const float* whh  = (const float*)d_in[4];
  const float* bih  = (const float*)d_in[5];
  const float* bhh  = (const float*)d_in[6];
  float* out = (float*)d_out;
  char* ws = (char*)d_ws;

  const int NL = 6, T = 512;
  const size_t sz_x = (size_t)T * 256 * 128 * 2;     // 33.55 MB
  const size_t sz_w = (size_t)NL * 768 * 256 * 2;    // 2.36 MB

  size_t o_x = 0;
  size_t o_wih = o_x + sz_x;
  size_t o_whh = o_wih + sz_w;
  size_t o_wfrag = o_whh + sz_w;
  size_t o_comb = o_wfrag + sz_w;                    // wfrag same total size
  size_t o_h = o_comb + (size_t)NL * 768 * 4;
  size_t o_dyn = o_h + (size_t)NL * 65536 * 4;

  int C = 32;
  while (C > 8 && o_dyn + (size_t)C * (NL * 2 * 131072 + NL * 393216) > ws_size) C >>= 1;
  const int NC = T / C;

  size_t o_ring = o_dyn;
  size_t o_gi = o_ring + (size_t)NL * 2 * C * 131072;

  u16* xf    = (u16*)(ws + o_x);
  u16* wihf  = (u16*)(ws + o_wih);
  u16* whhf  = (u16*)(ws + o_whh);
  u16* wfrag = (u16*)(ws + o_wfrag);
  float* comb = (float*)(ws + o_comb);
  float* hstate = (float*)(ws + o_h);
  u16* ringf = (u16*)(ws + o_ring);
  u16* gif   = (u16*)(ws + o_gi);

  auto ringptr = [&](int lyr, int c) -> u16* {
    return ringf + ((size_t)lyr * 2 + (c & 1)) * ((size_t)C * 65536);
  };

  auto cvt = [&](const float* s, u16* d, int n) {
    k_cvt<<<dim3((n / 4 + 255) / 256), dim3(256), 0, stream>>>(s, d, n);
  };
  cvt(x, xf, T * 256 * 128);
  cvt(wih0, wihf, 768 * 128);
  cvt(wih, wihf + 196608, 5 * 768 * 256);
  cvt(whh, whhf, 6 * 768 * 256);
  k_bias<<<dim3(18), dim3(256), 0, stream>>>(bih, bhh, comb);
  k_wprep<<<dim3(576), dim3(256), 0, stream>>>(whhf, wfrag);

  for (int wv = 0; wv < NL + NC - 1; ++wv) {
    int lmin = wv - (NC - 1); if (lmin < 0) lmin = 0;
    int lmax = wv < NL - 1 ? wv : NL - 1;
    int nact = lmax - lmin + 1;

    GTab gt; STab st;
    for (int zi = 0; zi < nact; ++zi) {
      int lyr = lmin + zi, c = wv - lyr;
      u16* gi_l = gif + (size_t)lyr * C * 196608;
      gt.e[zi].A = (lyr == 0) ? (xf + (size_t)c * C * 32768) : ringptr(lyr - 1, c);
      gt.e[zi].W = wihf + (size_t)lyr * 196608;
      gt.e[zi].bias = comb + lyr * 768;
      gt.e[zi].gi = gi_l;
      gt.e[zi].K = lyr ? 256 : 128;
      st.e[zi].Wf = wfrag + (size_t)lyr * 196608;   // 8 waves * 24576
      st.e[zi].bhh = bhh + lyr * 768;
      st.e[zi].gi = gi_l;
      st.e[zi].hin = (c == 0) ? (h0 + lyr * 65536) : (hstate + lyr * 65536);
      st.e[zi].hout = hstate + lyr * 65536;
      st.e[zi].outb = ringptr(lyr, c);
      st.e[zi].dfin = out + lyr * 65536;
    }
    k_gemm<<<dim3(2 * C, 6, nact), dim3(256), 0, stream>>>(gt);
    k_scan<<<dim3(16, nact), dim3(512), 0, stream>>>(st, C);
  }
}

// Round 17
// 1765.440 us; speedup vs baseline: 1.0764x; 1.0043x over previous
//
#include <hip/hip_runtime.h>

typedef _Float16 half_t;
typedef unsigned short u16;
typedef half_t half8 __attribute__((ext_vector_type(8)));
typedef float f32x4 __attribute__((ext_vector_type(4)));
typedef u16 u16x8 __attribute__((ext_vector_type(8)));
typedef u16 u16x4 __attribute__((ext_vector_type(4)));

// ---------- helpers ----------
static __device__ __forceinline__ float rcp_f(float x) { return __builtin_amdgcn_rcpf(x); }
static __device__ __forceinline__ float sigm_f(float x) { return rcp_f(1.0f + __expf(-x)); }
static __device__ __forceinline__ float tanh_f(float x) {
  float e = __expf(2.0f * x);  // inf-safe
  return 1.0f - 2.0f * rcp_f(e + 1.0f);
}
static __device__ __forceinline__ float h2f(u16 u) { union { u16 u; half_t h; } c; c.u = u; return (float)c.h; }
static __device__ __forceinline__ u16 f2h(float f) { union { u16 u; half_t h; } c; c.h = (half_t)f; return c.u; }

// swizzled offset (u16 units) into a [16][256] f16 LDS tile
static __device__ __forceinline__ int hoff2(int bb, int j) {
  int slot = j >> 3;
  int sw = (slot & ~7) | ((slot ^ bb) & 7);
  return bb * 256 + (sw << 3) + (j & 7);
}

// raw barrier: drain LDS only, leave VMEM in flight across the step boundary
#define STEP_BARRIER()                                         \
  do {                                                         \
    asm volatile("s_waitcnt lgkmcnt(0)" ::: "memory");         \
    __builtin_amdgcn_s_barrier();                              \
    asm volatile("" ::: "memory");                             \
  } while (0)

// ---------- per-layer launch tables (by-value kernel args) ----------
struct SP {
  const u16* Wf;  const float* bhh; const u16* gi;
  const float* hin; float* hout; u16* outb; float* dfin;
};
struct STab { SP e[6]; };
struct GP { const u16* A; const u16* W; const float* bias; u16* gi; int K; };
struct GTab { GP e[6]; };

// ---------- fp32 -> fp16 convert ----------
__global__ void k_cvt(const float* __restrict__ src, u16* __restrict__ dst, int n) {
  int i = (blockIdx.x * blockDim.x + threadIdx.x) * 4;
  if (i >= n) return;
  float4 v = *(const float4*)(src + i);
  u16x4 o;
  o[0] = f2h(v.x); o[1] = f2h(v.y); o[2] = f2h(v.z); o[3] = f2h(v.w);
  *(u16x4*)(dst + i) = o;
}

// ---------- combined bias: comb = bih + (row<512 ? bhh : 0) ----------
__global__ void k_bias(const float* __restrict__ bih, const float* __restrict__ bhh,
                       float* __restrict__ comb) {
  int i = blockIdx.x * 256 + threadIdx.x;
  if (i >= 6 * 768) return;
  int r = i % 768;
  comb[i] = bih[i] + (r < 512 ? bhh[i] : 0.0f);
}

// ---------- weight prep: repack Whh f16 into fragment-ordered blocks ----------
// Per (layer l, wave w): contiguous 24576 u16 = 48 KB:
//   rz : off = ((g*2+jt)*8+kf)*512 + lane*8 + e
//   n  : off = 16384 + (jt*8+kf)*512 + lane*8 + e
__global__ void k_wprep(const u16* __restrict__ whhf, u16* __restrict__ wfrag) {
  int gid = blockIdx.x * 256 + threadIdx.x;
  if (gid >= 147456) return;
  int lw = gid / 3072, grp = gid % 3072;
  int l = lw >> 3, w = lw & 7;
  const u16* wl = whhf + (size_t)l * 196608;
  int row, col, off;
  if (grp < 2048) {  // rz
    int sec = grp >> 6, lane = grp & 63;
    int g = sec >> 4, jt = (sec >> 3) & 1, kf = sec & 7;
    row = g * 256 + w * 32 + jt * 16 + (lane & 15);
    col = kf * 32 + (lane >> 4) * 8;
    off = sec * 512 + lane * 8;
  } else {           // n
    int grp2 = grp - 2048;
    int sec = grp2 >> 6, lane = grp2 & 63;
    int jt = sec >> 3, kf = sec & 7;
    row = 512 + w * 32 + jt * 16 + (lane & 15);
    col = kf * 32 + (lane >> 4) * 8;
    off = 16384 + sec * 512 + lane * 8;
  }
  *(u16x8*)&wfrag[((size_t)lw) * 24576 + off] = *(const u16x8*)&wl[row * 256 + col];
}

// ---------- gi GEMM (multi-layer): C[m][n] = A[m][k]*W[n][k] + bias[n] ----------
__global__ __launch_bounds__(256) void k_gemm(GTab tab) {
  const GP gp = tab.e[blockIdx.z];
  const u16* __restrict__ A = gp.A;
  const u16* __restrict__ W = gp.W;
  const float* __restrict__ bias = gp.bias;
  u16* __restrict__ gi = gp.gi;
  const int K = gp.K;

  __shared__ u16 Ab[2][128 * 32];
  __shared__ u16 Bb[2][128 * 32];
  const int tid = threadIdx.x;
  const int l = tid & 63, w = tid >> 6;
  const int wm = w & 1, wn = w >> 1;
  const int ln = l & 15, q = l >> 4;
  const int m0 = blockIdx.x * 128;
  const int n0 = blockIdx.y * 128;
  const int NT = K >> 5;

  float bz[4];
#pragma unroll
  for (int nt = 0; nt < 4; ++nt) bz[nt] = bias[n0 + wn * 64 + nt * 16 + ln];

  f32x4 acc[4][4];
#pragma unroll
  for (int mt = 0; mt < 4; ++mt)
#pragma unroll
    for (int nt = 0; nt < 4; ++nt) acc[mt][nt] = (f32x4){bz[nt], bz[nt], bz[nt], bz[nt]};

  auto stage = [&](int buf, int kt) {
    const int k0 = kt * 32;
#pragma unroll
    for (int qq = 0; qq < 2; ++qq) {
      int e = qq * 1024 + l * 16;
      int row = w * 32 + (e >> 6);
      int kk = (e & 63) >> 1;
      const u16* ga = A + (size_t)(m0 + row) * K + k0 + kk;
      const u16* gb = W + (size_t)(n0 + row) * K + k0 + kk;
      __builtin_amdgcn_global_load_lds((const __attribute__((address_space(1))) void*)ga,
                                       (__attribute__((address_space(3))) void*)&Ab[buf][row * 32 + kk],
                                       16, 0, 0);
      __builtin_amdgcn_global_load_lds((const __attribute__((address_space(1))) void*)gb,
                                       (__attribute__((address_space(3))) void*)&Bb[buf][row * 32 + kk],
                                       16, 0, 0);
    }
  };

  stage(0, 0);
  int cur = 0;
  for (int kt = 0; kt < NT; ++kt) {
    __syncthreads();  // staged tile must be complete
    if (kt + 1 < NT) stage(cur ^ 1, kt + 1);
    union { u16x8 u; half8 h; } af[4], bf[4];
#pragma unroll
    for (int mt = 0; mt < 4; ++mt)
      af[mt].u = *(const u16x8*)&Ab[cur][(wm * 64 + mt * 16 + ln) * 32 + q * 8];
#pragma unroll
    for (int nt = 0; nt < 4; ++nt)
      bf[nt].u = *(const u16x8*)&Bb[cur][(wn * 64 + nt * 16 + ln) * 32 + q * 8];
#pragma unroll
    for (int mt = 0; mt < 4; ++mt)
#pragma unroll
      for (int nt = 0; nt < 4; ++nt)
        acc[mt][nt] = __builtin_amdgcn_mfma_f32_16x16x32_f16(af[mt].h, bf[nt].h, acc[mt][nt], 0, 0, 0);
    cur ^= 1;
  }

#pragma unroll
  for (int mt = 0; mt < 4; ++mt) {
    int m = m0 + wm * 64 + mt * 16 + q * 4;
    int tloc = m >> 8, blk = (m >> 4) & 15, bb0 = m & 15;
#pragma unroll
    for (int nt = 0; nt < 4; ++nt) {
      int n = n0 + wn * 64 + nt * 16 + ln;
      u16x4 o;
#pragma unroll
      for (int i = 0; i < 4; ++i) o[i] = f2h(acc[mt][nt][i]);
      *(u16x4*)&gi[(((size_t)tloc * 16 + blk) * 768 + n) * 16 + bb0] = o;
    }
  }
}

// ---------- persistent-weight GRU scan (multi-layer wavefront) ----------
// grid (16, nact). Weights read from the fragment-ordered wfrag buffer:
// fully coalesced register loads (r,z) + global_load_lds staging (n-gate).
__global__ __launch_bounds__(512, 2) void k_scan(STab tab, int tcount) {
  const SP p = tab.e[blockIdx.y];
  const u16* __restrict__ Wf = p.Wf;     // layer base in wfrag
  const float* __restrict__ bhh = p.bhh;
  const u16* __restrict__ gi = p.gi;
  const float* hin = p.hin;
  float* hout = p.hout;
  u16* __restrict__ outb = p.outb;
  float* __restrict__ dfin = p.dfin;

  __shared__ u16 hl[2][16 * 256];        // 16 KB
  __shared__ u16 wn[8][2][8][512];       // 128 KB: n-gate weights, per-wave slices
  const int tid = threadIdx.x;
  const int l = tid & 63, w = tid >> 6;
  const int ln = l & 15, q = l >> 4;
  const int j0 = w * 32;
  const int bx = blockIdx.x;
  const int bb0g = bx * 16;

  union u128 { u16x8 u; half8 h; };

  const u16* wb = Wf + (size_t)w * 24576;  // this wave's 48 KB fragment block

  // r,z weight fragments: 32 coalesced b128 loads (512 B/lane contiguous)
  u128 Bw[2][2][8];
#pragma unroll
  for (int g = 0; g < 2; ++g)
#pragma unroll
    for (int jt = 0; jt < 2; ++jt)
#pragma unroll
      for (int kf = 0; kf < 8; ++kf)
        Bw[g][jt][kf].u = *(const u16x8*)&wb[(((g * 2 + jt) * 8) + kf) * 512 + l * 8];
#pragma unroll
  for (int g = 0; g < 2; ++g)
#pragma unroll
    for (int jt = 0; jt < 2; ++jt)
#pragma unroll
      for (int kf = 0; kf < 8; ++kf)
        asm volatile("" : "+v"(Bw[g][jt][kf].u));

  // n-gate weights -> LDS via async global->LDS (dest = uniform base + lane*16)
#pragma unroll
  for (int jt = 0; jt < 2; ++jt)
#pragma unroll
    for (int kf = 0; kf < 8; ++kf)
      __builtin_amdgcn_global_load_lds(
          (const __attribute__((address_space(1))) void*)&wb[16384 + (jt * 8 + kf) * 512 + l * 8],
          (__attribute__((address_space(3))) void*)&wn[w][jt][kf][l * 8], 16, 0, 0);

  // n-gate recurrent bias
  float bn[2];
  bn[0] = bhh[512 + j0 + ln];
  bn[1] = bhh[512 + j0 + 16 + ln];

  // fp32 recurrent state
  float hst[2][4];
#pragma unroll
  for (int jt = 0; jt < 2; ++jt)
#pragma unroll
    for (int i = 0; i < 4; ++i)
      hst[jt][i] = hin[(bb0g + q * 4 + i) * 256 + j0 + jt * 16 + ln];

  // seed h LDS (buffer 0)
#pragma unroll
  for (int jt = 0; jt < 2; ++jt)
#pragma unroll
    for (int i = 0; i < 4; ++i)
      hl[0][hoff2(q * 4 + i, j0 + jt * 16 + ln)] = f2h(hst[jt][i]);

  // gv for t=0
  u16x4 gv[3][2];
  {
    const u16* p2 = gi + ((size_t)bx * 768 + j0 + ln) * 16 + q * 4;
#pragma unroll
    for (int g = 0; g < 3; ++g)
#pragma unroll
      for (int jt = 0; jt < 2; ++jt)
        gv[g][jt] = *(const u16x4*)(p2 + (g * 256 + jt * 16) * 16);
  }

  // drain wn staging (global_load_lds completion is not register-tracked)
  asm volatile("s_waitcnt vmcnt(0)" ::: "memory");

  int cur = 0;
  for (int t = 0; t < tcount; ++t) {
    STEP_BARRIER();  // hl[cur] complete; VMEM stays in flight
    u16* hlc = &hl[cur][0];
    u16* hln = &hl[cur ^ 1][0];

    // write h entering this step (local output index t-1; dup at t==0 is
    // overwritten by the next step's write)
    {
      int ot = t - 1; if (ot < 0) ot = 0;
      int obb = tid >> 5, oj = (tid & 31) << 3;
      u16x8 v = *(const u16x8*)&hlc[hoff2(obb, oj)];
      *(u16x8*)&outb[((size_t)ot * 256 + bb0g + obb) * 256 + oj] = v;
    }

    f32x4 ar[2], az[2], an[2];
#pragma unroll
    for (int jt = 0; jt < 2; ++jt) {
      ar[jt] = (f32x4){0.f, 0.f, 0.f, 0.f};
      az[jt] = (f32x4){0.f, 0.f, 0.f, 0.f};
      an[jt] = (f32x4){bn[jt], bn[jt], bn[jt], bn[jt]};
    }

#pragma unroll
    for (int kf = 0; kf < 8; ++kf) {
      u128 av, w0, w1;
      av.u = *(const u16x8*)&hlc[hoff2(ln, kf * 32 + q * 8)];
      w0.u = *(const u16x8*)&wn[w][0][kf][l * 8];
      w1.u = *(const u16x8*)&wn[w][1][kf][l * 8];
#pragma unroll
      for (int jt = 0; jt < 2; ++jt) {
        ar[jt] = __builtin_amdgcn_mfma_f32_16x16x32_f16(av.h, Bw[0][jt][kf].h, ar[jt], 0, 0, 0);
        az[jt] = __builtin_amdgcn_mfma_f32_16x16x32_f16(av.h, Bw[1][jt][kf].h, az[jt], 0, 0, 0);
      }
      an[0] = __builtin_amdgcn_mfma_f32_16x16x32_f16(av.h, w0.h, an[0], 0, 0, 0);
      an[1] = __builtin_amdgcn_mfma_f32_16x16x32_f16(av.h, w1.h, an[1], 0, 0, 0);
    }

    // elementwise + state update + LDS write for next step
#pragma unroll
    for (int jt = 0; jt < 2; ++jt)
#pragma unroll
      for (int i = 0; i < 4; ++i) {
        float r = sigm_f(h2f(gv[0][jt][i]) + ar[jt][i]);
        float z = sigm_f(h2f(gv[1][jt][i]) + az[jt][i]);
        float n = tanh_f(h2f(gv[2][jt][i]) + r * an[jt][i]);
        float hv = n + z * (hst[jt][i] - n);
        hst[jt][i] = hv;
        hln[hoff2(q * 4 + i, j0 + jt * 16 + ln)] = f2h(hv);
      }

    // prefetch gv for t+1
    {
      int tn = t + 1 < tcount ? t + 1 : tcount - 1;
      const u16* p2 = gi + (((size_t)tn * 16 + bx) * 768 + j0 + ln) * 16 + q * 4;
#pragma unroll
      for (int g = 0; g < 3; ++g)
#pragma unroll
        for (int jt = 0; jt < 2; ++jt)
          gv[g][jt] = *(const u16x4*)(p2 + (g * 256 + jt * 16) * 16);
    }
    cur ^= 1;
  }

  STEP_BARRIER();
  {  // final output row of this chunk
    int obb = tid >> 5, oj = (tid & 31) << 3;
    u16x8 v = *(const u16x8*)&hl[cur][hoff2(obb, oj)];
    *(u16x8*)&outb[((size_t)(tcount - 1) * 256 + bb0g + obb) * 256 + oj] = v;
  }
  // persist fp32 state + h_n slice (ascending chunk order => last chunk wins)
#pragma unroll
  for (int jt = 0; jt < 2; ++jt)
#pragma unroll
    for (int i = 0; i < 4; ++i) {
      int idx = (bb0g + q * 4 + i) * 256 + j0 + jt * 16 + ln;
      hout[idx] = hst[jt][i];
      dfin[idx] = hst[jt][i];
    }
}

// ---------- host: launch-wavefront layer pipeline ----------
extern "C" void kernel_launch(void* const* d_in, const int* in_sizes, int n_in,
                              void* d_out, int out_size, void* d_ws, size_t ws_size,
                              hipStream_t stream) {
  const float* x    = (const float*)d_in[0];
  const float* h0   = (const float*)d_in[1];
  const float* wih0 = (const float*)d_in[2];
  const float* wih  = (const float*)d_in[3];
  const float* whh  = (const float*)d_in[4];
  const float* bih  = (const float*)d_in[5];
  const float* bhh  = (const float*)d_in[6];
  float* out = (float*)d_out;
  char* ws = (char*)d_ws;

  const int NL = 6, T = 512;
  const size_t sz_x = (size_t)T * 256 * 128 * 2;
  const size_t sz_w = (size_t)NL * 768 * 256 * 2;

  size_t o_x = 0;
  size_t o_wih = o_x + sz_x;
  size_t o_whh = o_wih + sz_w;
  size_t o_wfrag = o_whh + sz_w;
  size_t o_comb = o_wfrag + sz_w;
  size_t o_h = o_comb + (size_t)NL * 768 * 4;
  size_t o_dyn = o_h + (size_t)NL * 65536 * 4;

  int C = 32;
  while (C > 8 && o_dyn + (size_t)C * (NL * 2 * 131072 + NL * 393216) > ws_size) C >>= 1;
  const int NC = T / C;

  size_t o_ring = o_dyn;
  size_t o_gi = o_ring + (size_t)NL * 2 * C * 131072;

  u16* xf    = (u16*)(ws + o_x);
  u16* wihf  = (u16*)(ws + o_wih);
  u16* whhf  = (u16*)(ws + o_whh);
  u16* wfrag = (u16*)(ws + o_wfrag);
  float* comb = (float*)(ws + o_comb);
  float* hstate = (float*)(ws + o_h);
  u16* ringf = (u16*)(ws + o_ring);
  u16* gif   = (u16*)(ws + o_gi);

  auto ringptr = [&](int lyr, int c) -> u16* {
    return ringf + ((size_t)lyr * 2 + (c & 1)) * ((size_t)C * 65536);
  };

  auto cvt = [&](const float* s, u16* d, int n) {
    k_cvt<<<dim3((n / 4 + 255) / 256), dim3(256), 0, stream>>>(s, d, n);
  };
  cvt(x, xf, T * 256 * 128);
  cvt(wih0, wihf, 768 * 128);
  cvt(wih, wihf + 196608, 5 * 768 * 256);
  cvt(whh, whhf, 6 * 768 * 256);
  k_bias<<<dim3(18), dim3(256), 0, stream>>>(bih, bhh, comb);
  k_wprep<<<dim3(576), dim3(256), 0, stream>>>(whhf, wfrag);

  for (int wv = 0; wv < NL + NC - 1; ++wv) {
    int lmin = wv - (NC - 1); if (lmin < 0) lmin = 0;
    int lmax = wv < NL - 1 ? wv : NL - 1;
    int nact = lmax - lmin + 1;

    GTab gt; STab st;
    for (int zi = 0; zi < nact; ++zi) {
      int lyr = lmin + zi, c = wv - lyr;
      u16* gi_l = gif + (size_t)lyr * C * 196608;
      gt.e[zi].A = (lyr == 0) ? (xf + (size_t)c * C * 32768) : ringptr(lyr - 1, c);
      gt.e[zi].W = wihf + (size_t)lyr * 196608;
      gt.e[zi].bias = comb + lyr * 768;
      gt.e[zi].gi = gi_l;
      gt.e[zi].K = lyr ? 256 : 128;
      st.e[zi].Wf = wfrag + (size_t)lyr * 196608;
      st.e[zi].bhh = bhh + lyr * 768;
      st.e[zi].gi = gi_l;
      st.e[zi].hin = (c == 0) ? (h0 + lyr * 65536) : (hstate + lyr * 65536);
      st.e[zi].hout = hstate + lyr * 65536;
      st.e[zi].outb = ringptr(lyr, c);
      st.e[zi].dfin = out + lyr * 65536;
    }
    k_gemm<<<dim3(2 * C, 6, nact), dim3(256), 0, stream>>>(gt);
    k_scan<<<dim3(16, nact), dim3(512), 0, stream>>>(st, C);
  }
}